// Round 1
// baseline (458.195 us; speedup 1.0000x reference)
//
#include <hip/hip_runtime.h>
#include <hip/hip_bf16.h>

// MHA forward, MI355X gfx950.
// B=2, S=2048, D=1024, H=16, DK=64.
// d_in: 0 q,1 k,2 v,3 mask,4 w_q,5 b_q,6 w_k,7 b_k,8 w_v,9 b_v,10 w_o,11 b_o
// d_out: [out (2,2048,1024) f32][attn_weights (2,16,2048,2048) f32]
// ws: qh | kh | vh | vhT | ctx (bf16, 8MB each) | flag (int)

#define DEVI __device__ __forceinline__

typedef short bf16x8 __attribute__((ext_vector_type(8)));
typedef float f32x4  __attribute__((ext_vector_type(4)));

static constexpr int S = 2048;
static constexpr int D = 1024;
static constexpr int H = 16;
static constexpr int DK = 64;
static constexpr int NT = 2 * S;        // 4096 rows
static constexpr long WS_SEG = 8388608; // bytes per bf16 segment (4.19M elems * 2B)

DEVI unsigned short f2bf(float f) {
  unsigned u = __float_as_uint(f);
  unsigned r = u + 0x7fffu + ((u >> 16) & 1u);  // RNE
  return (unsigned short)(r >> 16);
}

// ---------------------------------------------------------------- mask flag
__global__ void flag_init_kernel(int* flag) { *flag = 1; }

__global__ void mask_and_kernel(const int* __restrict__ mask, int* __restrict__ flag) {
  const int4* m4 = (const int4*)mask;
  int acc = ~0;
  int stride = gridDim.x * blockDim.x;
  for (int i = blockIdx.x * blockDim.x + threadIdx.x; i < S * S / 4; i += stride) {
    int4 v = m4[i];
    acc &= v.x & v.y & v.z & v.w;
  }
  // acc != 0 implies every element nonzero (0 would zero acc forever).
  if (acc == 0) atomicAnd(flag, 0);
}

// ---------------------------------------------------------------- projection GEMM
// C[n][o] = sum_i A[n][i] * W[o][i] (+bias, *scale).  A: [NT][1024], W: [1024][1024] f32.
// MODE 0: bf16 head-split out [B][H][S][DK].  MODE 1: f32 flat out [NT][D].
// 512 threads, 128x128 tile, BK=64, XOR-swizzled LDS.
template <int MODE, bool ABF16>
__global__ __launch_bounds__(512) void proj_gemm(const void* __restrict__ Ap,
                                                 const float* __restrict__ W,
                                                 const float* __restrict__ bias,
                                                 void* __restrict__ outp,
                                                 float out_scale) {
  __shared__ short lA[128 * 64];  // 16 KB, row stride 128 B, swizzled
  __shared__ short lB[128 * 64];

  const int t = threadIdx.x;
  const int lane = t & 63, w = t >> 6;   // 8 waves
  const int wr = w >> 2, wc = w & 3;     // wave grid 2x4: wave tile 64x32
  const int r0 = blockIdx.x * 128;       // N tile
  const int c0 = blockIdx.y * 128;       // O tile

  const f32x4 zero4 = {0.f, 0.f, 0.f, 0.f};
  f32x4 acc[4][2];
#pragma unroll
  for (int m = 0; m < 4; ++m)
#pragma unroll
    for (int n = 0; n < 2; ++n) acc[m][n] = zero4;

  const int srow = t >> 2;          // 0..127 staging row
  const int scol = (t & 3) * 16;    // 0,16,32,48

  for (int kt = 0; kt < 16; ++kt) {
    const int k0 = kt * 64;
    // ---- stage A
    if (ABF16) {
      const unsigned short* A = (const unsigned short*)Ap;
      const unsigned short* src = A + (long)(r0 + srow) * 1024 + k0 + scol;
#pragma unroll
      for (int g = 0; g < 2; ++g) {
        bf16x8 v = *(const bf16x8*)(src + g * 8);
        int byte = (srow * 128 + (scol + g * 8) * 2) ^ ((srow & 7) << 4);
        *(bf16x8*)((char*)lA + byte) = v;
      }
    } else {
      const float* A = (const float*)Ap;
      const float4* src = (const float4*)(A + (long)(r0 + srow) * 1024 + k0 + scol);
#pragma unroll
      for (int g = 0; g < 2; ++g) {
        float4 a0 = src[2 * g], a1 = src[2 * g + 1];
        bf16x8 pk;
        pk[0] = f2bf(a0.x); pk[1] = f2bf(a0.y); pk[2] = f2bf(a0.z); pk[3] = f2bf(a0.w);
        pk[4] = f2bf(a1.x); pk[5] = f2bf(a1.y); pk[6] = f2bf(a1.z); pk[7] = f2bf(a1.w);
        int byte = (srow * 128 + (scol + g * 8) * 2) ^ ((srow & 7) << 4);
        *(bf16x8*)((char*)lA + byte) = pk;
      }
    }
    // ---- stage B (W always f32)
    {
      const float4* src = (const float4*)(W + (long)(c0 + srow) * 1024 + k0 + scol);
#pragma unroll
      for (int g = 0; g < 2; ++g) {
        float4 a0 = src[2 * g], a1 = src[2 * g + 1];
        bf16x8 pk;
        pk[0] = f2bf(a0.x); pk[1] = f2bf(a0.y); pk[2] = f2bf(a0.z); pk[3] = f2bf(a0.w);
        pk[4] = f2bf(a1.x); pk[5] = f2bf(a1.y); pk[6] = f2bf(a1.z); pk[7] = f2bf(a1.w);
        int byte = (srow * 128 + (scol + g * 8) * 2) ^ ((srow & 7) << 4);
        *(bf16x8*)((char*)lB + byte) = pk;
      }
    }
    __syncthreads();
    // ---- compute
#pragma unroll
    for (int ks = 0; ks < 2; ++ks) {
      bf16x8 af[4];
#pragma unroll
      for (int m = 0; m < 4; ++m) {
        int row = wr * 64 + m * 16 + (lane & 15);
        int byte = (row * 128 + ks * 64 + (lane >> 4) * 16) ^ ((row & 7) << 4);
        af[m] = *(const bf16x8*)((const char*)lA + byte);
      }
#pragma unroll
      for (int n = 0; n < 2; ++n) {
        int row = wc * 32 + n * 16 + (lane & 15);
        int byte = (row * 128 + ks * 64 + (lane >> 4) * 16) ^ ((row & 7) << 4);
        bf16x8 bfr = *(const bf16x8*)((const char*)lB + byte);
#pragma unroll
        for (int m = 0; m < 4; ++m)
          acc[m][n] = __builtin_amdgcn_mfma_f32_16x16x32_bf16(af[m], bfr, acc[m][n], 0, 0, 0);
      }
    }
    __syncthreads();
  }

  // ---- epilogue
#pragma unroll
  for (int n = 0; n < 2; ++n) {
    int gc = c0 + wc * 32 + n * 16 + (lane & 15);
    float bi = bias[gc];
#pragma unroll
    for (int m = 0; m < 4; ++m) {
      int grb = r0 + wr * 64 + m * 16 + ((lane >> 4) << 2);
#pragma unroll
      for (int j = 0; j < 4; ++j) {
        int gr = grb + j;
        float val = (acc[m][n][j] + bi) * out_scale;
        if (MODE == 0) {
          int b = gr >> 11, s = gr & 2047, h = gc >> 6, d = gc & 63;
          ((unsigned short*)outp)[(((b * 16 + h) * 2048 + s) * 64) + d] = f2bf(val);
        } else {
          ((float*)outp)[(long)gr * 1024 + gc] = val;
        }
      }
    }
  }
}

// ---------------------------------------------------------------- V transpose
// Vh [B][H][S][DK] -> VhT [B][H][DK][S]
__global__ __launch_bounds__(256) void transpose_v(const unsigned short* __restrict__ Vh,
                                                   unsigned short* __restrict__ VhT) {
  int bh = blockIdx.x >> 5;
  int st = blockIdx.x & 31;
  __shared__ unsigned short tb[64][65];
  const unsigned short* src = Vh + ((long)bh * 2048 + st * 64) * 64;
  unsigned short* dst = VhT + (long)bh * 64 * 2048 + st * 64;
  for (int i = threadIdx.x; i < 64 * 64; i += 256) {
    int s = i >> 6, d = i & 63;
    tb[d][s] = src[s * 64 + d];
  }
  __syncthreads();
  for (int i = threadIdx.x; i < 64 * 64; i += 256) {
    int d = i >> 6, s = i & 63;
    dst[d * 2048 + s] = tb[d][s];
  }
}

// ---------------------------------------------------------------- attention
// One block = one (b,h) and 16 query rows. 512 threads / 8 waves.
// Wave w owns score columns {ct*128 + w*16 + (lane&15)} per column-tile ct.
__global__ __launch_bounds__(512) void attn_kernel(const unsigned short* __restrict__ Qh,
                                                   const unsigned short* __restrict__ Kh,
                                                   const unsigned short* __restrict__ VhT,
                                                   const int* __restrict__ mask,
                                                   const int* __restrict__ flag,
                                                   float* __restrict__ Pout,
                                                   unsigned short* __restrict__ ctx) {
  __shared__ short lK[128 * 64];    // 16 KB K tile, swizzled
  __shared__ short lP[16 * 1024];   // 32 KB P half (bf16) / reduce scratch (f32 [8][1024])
  __shared__ float rred[8][16];

  const int t = threadIdx.x, lane = t & 63, w = t >> 6;
  const int bh = blockIdx.x >> 7;       // 0..31
  const int rt = blockIdx.x & 127;
  const int q0 = rt * 16;
  const unsigned short* Kbase = Kh + (long)bh * S * DK;
  const unsigned short* Vbase = VhT + (long)bh * DK * S;

  // Q fragments (A operand), rows q0..q0+15
  const int qr = lane & 15, kc = lane >> 4;
  bf16x8 aq0, aq1;
  {
    const unsigned short* qrow = Qh + ((long)bh * S + q0 + qr) * DK;
    aq0 = *(const bf16x8*)(qrow + kc * 8);
    aq1 = *(const bf16x8*)(qrow + 32 + kc * 8);
  }

  const f32x4 zero4 = {0.f, 0.f, 0.f, 0.f};
  f32x4 sacc[16];

  const int srow = t >> 2;          // staging: 0..127
  const int scol = (t & 3) * 16;

  // ---- scores: S[q][col] = sum_d Q[q][d] K[col][d]
#pragma unroll
  for (int ct = 0; ct < 16; ++ct) {
    {
      const unsigned short* src = Kbase + (long)(ct * 128 + srow) * 64 + scol;
      bf16x8 v0 = *(const bf16x8*)(src);
      bf16x8 v1 = *(const bf16x8*)(src + 8);
      int b0 = (srow * 128 + scol * 2) ^ ((srow & 7) << 4);
      int b1 = (srow * 128 + scol * 2 + 16) ^ ((srow & 7) << 4);
      *(bf16x8*)((char*)lK + b0) = v0;
      *(bf16x8*)((char*)lK + b1) = v1;
    }
    __syncthreads();
    {
      int row = w * 16 + (lane & 15);
      int sw = (row & 7) << 4;
      int c0b = (row * 128 + (lane >> 4) * 16) ^ sw;
      int c1b = (row * 128 + 64 + (lane >> 4) * 16) ^ sw;
      bf16x8 bk0 = *(const bf16x8*)((const char*)lK + c0b);
      bf16x8 bk1 = *(const bf16x8*)((const char*)lK + c1b);
      f32x4 s = zero4;
      s = __builtin_amdgcn_mfma_f32_16x16x32_bf16(aq0, bk0, s, 0, 0, 0);
      s = __builtin_amdgcn_mfma_f32_16x16x32_bf16(aq1, bk1, s, 0, 0, 0);
      sacc[ct] = s;
    }
    __syncthreads();
  }

  // ---- mask (slow path only when mask has zeros)
  const bool allones = (*flag != 0);
  if (!allones) {
#pragma unroll
    for (int ct = 0; ct < 16; ++ct) {
      int col = ct * 128 + w * 16 + (lane & 15);
#pragma unroll
      for (int j = 0; j < 4; ++j) {
        int qg = q0 + ((lane >> 4) << 2) + j;
        if (mask[(long)qg * S + col] == 0) sacc[ct][j] = -1e9f;
      }
    }
  }

  // ---- softmax (rows 4*(lane>>4)+j live across lanes (lane&15) x 8 waves)
  float mrow[4];
#pragma unroll
  for (int j = 0; j < 4; ++j) {
    float m = sacc[0][j];
#pragma unroll
    for (int ct = 1; ct < 16; ++ct) m = fmaxf(m, sacc[ct][j]);
#pragma unroll
    for (int off = 1; off < 16; off <<= 1) m = fmaxf(m, __shfl_xor(m, off));
    mrow[j] = m;
  }
  if ((lane & 15) == 0) {
#pragma unroll
    for (int j = 0; j < 4; ++j) rred[w][((lane >> 4) << 2) + j] = mrow[j];
  }
  __syncthreads();
#pragma unroll
  for (int j = 0; j < 4; ++j) {
    float m = rred[0][((lane >> 4) << 2) + j];
#pragma unroll
    for (int ww = 1; ww < 8; ++ww) m = fmaxf(m, rred[ww][((lane >> 4) << 2) + j]);
    mrow[j] = m;
  }
  __syncthreads();

  float zsum[4] = {0.f, 0.f, 0.f, 0.f};
#pragma unroll
  for (int ct = 0; ct < 16; ++ct)
#pragma unroll
    for (int j = 0; j < 4; ++j) {
      float p = __expf(sacc[ct][j] - mrow[j]);
      sacc[ct][j] = p;
      zsum[j] += p;
    }
#pragma unroll
  for (int j = 0; j < 4; ++j) {
    float s = zsum[j];
#pragma unroll
    for (int off = 1; off < 16; off <<= 1) s += __shfl_xor(s, off);
    zsum[j] = s;
  }
  if ((lane & 15) == 0) {
#pragma unroll
    for (int j = 0; j < 4; ++j) rred[w][((lane >> 4) << 2) + j] = zsum[j];
  }
  __syncthreads();
  float inv[4];
#pragma unroll
  for (int j = 0; j < 4; ++j) {
    float z = rred[0][((lane >> 4) << 2) + j];
#pragma unroll
    for (int ww = 1; ww < 8; ++ww) z += rred[ww][((lane >> 4) << 2) + j];
    inv[j] = 1.0f / z;
  }

  // ---- P write (f32 to d_out) + bf16 to LDS; PV in two column halves
  float* Prow = Pout + ((long)bh * S + q0) * S;
  f32x4 pacc[4];
#pragma unroll
  for (int n = 0; n < 4; ++n) pacc[n] = zero4;

#pragma unroll
  for (int hf = 0; hf < 2; ++hf) {
#pragma unroll
    for (int c2 = 0; c2 < 8; ++c2) {
      int ct = hf * 8 + c2;
      int col = ct * 128 + w * 16 + (lane & 15);
      int ccol = col - hf * 1024;
#pragma unroll
      for (int j = 0; j < 4; ++j) {
        int r = ((lane >> 4) << 2) + j;
        float pv = sacc[ct][j] * inv[j];
        Prow[(long)r * S + col] = pv;
        int byte = (r * 2048 + ccol * 2) ^ ((r & 7) << 4);
        *(unsigned short*)((char*)lP + byte) = f2bf(pv);
      }
    }
    __syncthreads();
    // PV: wave w handles k in [w*128, w*128+128) of this half
#pragma unroll
    for (int kk = 0; kk < 4; ++kk) {
      int kb = w * 128 + kk * 32;
      int row = lane & 15;
      int byteA = (row * 2048 + (kb + (lane >> 4) * 8) * 2) ^ ((row & 7) << 4);
      bf16x8 ap = *(const bf16x8*)((const char*)lP + byteA);
#pragma unroll
      for (int n = 0; n < 4; ++n) {
        const unsigned short* vrow =
            Vbase + (long)(n * 16 + (lane & 15)) * S + hf * 1024 + kb + (lane >> 4) * 8;
        bf16x8 bv = *(const bf16x8*)vrow;
        pacc[n] = __builtin_amdgcn_mfma_f32_16x16x32_bf16(ap, bv, pacc[n], 0, 0, 0);
      }
    }
    __syncthreads();
  }

  // ---- cross-wave K-slice reduce via lP (reused as f32 [8][1024])
  float* red = (float*)lP;
#pragma unroll
  for (int n = 0; n < 4; ++n)
#pragma unroll
    for (int j = 0; j < 4; ++j)
      red[w * 1024 + (((lane >> 4) << 2) + j) * 64 + n * 16 + (lane & 15)] = pacc[n][j];
  __syncthreads();
#pragma unroll
  for (int i = 0; i < 2; ++i) {
    int idx = t * 2 + i;
    float s = red[idx];
#pragma unroll
    for (int ww = 1; ww < 8; ++ww) s += red[ww * 1024 + idx];
    int qrow = idx >> 6, d = idx & 63;
    int b = bh >> 4, h = bh & 15;
    ctx[((long)(b * S + q0 + qrow)) * D + h * 64 + d] = f2bf(s);
  }
}

// ---------------------------------------------------------------- launch
extern "C" void kernel_launch(void* const* d_in, const int* in_sizes, int n_in,
                              void* d_out, int out_size, void* d_ws, size_t ws_size,
                              hipStream_t stream) {
  const float* q = (const float*)d_in[0];
  const float* k = (const float*)d_in[1];
  const float* v = (const float*)d_in[2];
  const int* mask = (const int*)d_in[3];
  const float* w_q = (const float*)d_in[4];
  const float* b_q = (const float*)d_in[5];
  const float* w_k = (const float*)d_in[6];
  const float* b_k = (const float*)d_in[7];
  const float* w_v = (const float*)d_in[8];
  const float* b_v = (const float*)d_in[9];
  const float* w_o = (const float*)d_in[10];
  const float* b_o = (const float*)d_in[11];

  char* wsb = (char*)d_ws;
  unsigned short* qh  = (unsigned short*)(wsb + 0 * WS_SEG);
  unsigned short* kh  = (unsigned short*)(wsb + 1 * WS_SEG);
  unsigned short* vh  = (unsigned short*)(wsb + 2 * WS_SEG);
  unsigned short* vhT = (unsigned short*)(wsb + 3 * WS_SEG);
  unsigned short* ctx = (unsigned short*)(wsb + 4 * WS_SEG);
  int* flag = (int*)(wsb + 5 * WS_SEG);

  float* out_f = (float*)d_out;                 // [4096][1024]
  float* attnW = out_f + (long)NT * D;          // [2][16][2048][2048]

  flag_init_kernel<<<1, 1, 0, stream>>>(flag);
  mask_and_kernel<<<1024, 256, 0, stream>>>(mask, flag);

  const float qscale = 0.125f;  // 1/sqrt(64)
  proj_gemm<0, false><<<dim3(32, 8), 512, 0, stream>>>((const void*)q, w_q, b_q, (void*)qh, qscale);
  proj_gemm<0, false><<<dim3(32, 8), 512, 0, stream>>>((const void*)k, w_k, b_k, (void*)kh, 1.0f);
  proj_gemm<0, false><<<dim3(32, 8), 512, 0, stream>>>((const void*)v, w_v, b_v, (void*)vh, 1.0f);
  transpose_v<<<1024, 256, 0, stream>>>(vh, vhT);
  attn_kernel<<<4096, 512, 0, stream>>>(qh, kh, vhT, mask, flag, attnW, ctx);
  proj_gemm<1, true><<<dim3(32, 8), 512, 0, stream>>>((const void*)ctx, w_o, b_o, (void*)d_out, 1.0f);
}

// Round 2
// 264.742 us; speedup vs baseline: 1.7307x; 1.7307x over previous
//
#include <hip/hip_runtime.h>
#include <hip/hip_bf16.h>

// MHA forward, MI355X gfx950.
// B=2, S=2048, D=1024, H=16, DK=64.
// d_in: 0 q,1 k,2 v,3 mask,4 w_q,5 b_q,6 w_k,7 b_k,8 w_v,9 b_v,10 w_o,11 b_o
// d_out: [out (2,2048,1024) f32][attn_weights (2,16,2048,2048) f32]
//
// Strategy: everything bf16 frag-major (one MFMA B/A fragment = 16x32 = 1KB,
// lane-ordered: lane l's 16B at offset l*16), so GEMMs and attention read
// operand fragments directly from global (L2-hot) with zero LDS staging and
// zero barriers in the MFMA streams.
//
// ws layout (exactly 41943044 bytes, proven budget):
//   A0 (8.39MB): qbf  -> khf      (K frag, aliased after q-proj)
//   A1 (8.39MB): kbf  -> vhf      (V frag, aliased after k-proj)
//   A2 (8.39MB): vbf  -> ctxf     (ctx A-frag, aliased after v-proj)
//   A3 (8.39MB): qhf              (Q frag)
//   W  (4x2MB):  wqf wkf wvf wof  (W frags)
//   flag (4B)

#define DEVI __device__ __forceinline__

typedef short bf16x8 __attribute__((ext_vector_type(8)));
typedef float f32x4  __attribute__((ext_vector_type(4)));
typedef unsigned short u16x4 __attribute__((ext_vector_type(4)));

static constexpr int S = 2048;
static constexpr int DK = 64;
static constexpr size_t A_ELEMS = 4194304;   // 4096*1024 (per A-tensor)
static constexpr size_t W_ELEMS = 1048576;   // 1024*1024 (per weight)
static constexpr size_t BH_ELEMS = 131072;   // 2048*64 (per b,h slice)

DEVI unsigned short f2bf(float f) {
  unsigned u = __float_as_uint(f);
  unsigned r = u + 0x7fffu + ((u >> 16) & 1u);  // RNE
  return (unsigned short)(r >> 16);
}

// ---------------------------------------------------------------- mask flag
__global__ void flag_init_kernel(int* flag) { *flag = 1; }

__global__ void mask_and_kernel(const int* __restrict__ mask, int* __restrict__ flag) {
  const int4* m4 = (const int4*)mask;
  int acc = ~0;
  int stride = gridDim.x * blockDim.x;
  for (int i = blockIdx.x * blockDim.x + threadIdx.x; i < S * S / 4; i += stride) {
    int4 v = m4[i];
    acc &= v.x & v.y & v.z & v.w;
  }
  if (acc == 0) atomicAnd(flag, 0);
}

// ---------------------------------------------------------------- converts
// A-frag layout over [4096 rows][1024 ch]: elem (r,i) ->
//   (((r>>4)*32 + (i>>5))<<9) + (((i>>3)&3)<<7) + ((r&15)<<3) + (i&7)
__global__ __launch_bounds__(256) void convert_a(const float* __restrict__ q,
                                                 const float* __restrict__ k,
                                                 const float* __restrict__ v,
                                                 unsigned short* __restrict__ qb,
                                                 unsigned short* __restrict__ kb,
                                                 unsigned short* __restrict__ vb) {
  const int z = blockIdx.y;
  const float* src = (z == 0) ? q : (z == 1) ? k : v;
  unsigned short* dst = (z == 0) ? qb : (z == 1) ? kb : vb;
  const int t = blockIdx.x * 256 + threadIdx.x;  // 0..524287
  const int r = t >> 7, i0 = (t & 127) << 3;
  const float4* s4 = (const float4*)(src + (size_t)r * 1024 + i0);
  float4 a = s4[0], b = s4[1];
  bf16x8 pk;
  pk[0] = (short)f2bf(a.x); pk[1] = (short)f2bf(a.y);
  pk[2] = (short)f2bf(a.z); pk[3] = (short)f2bf(a.w);
  pk[4] = (short)f2bf(b.x); pk[5] = (short)f2bf(b.y);
  pk[6] = (short)f2bf(b.z); pk[7] = (short)f2bf(b.w);
  size_t addr = ((size_t)((r >> 4) * 32 + (i0 >> 5)) << 9) + (((i0 >> 3) & 3) << 7) + ((r & 15) << 3);
  *(bf16x8*)(dst + addr) = pk;
}

// W-frag layout over [1024 o][1024 i]: same formula with r->o.
__global__ __launch_bounds__(256) void convert_w(const float* __restrict__ w0,
                                                 const float* __restrict__ w1,
                                                 const float* __restrict__ w2,
                                                 const float* __restrict__ w3,
                                                 unsigned short* __restrict__ dstbase) {
  const int z = blockIdx.y;
  const float* src = (z == 0) ? w0 : (z == 1) ? w1 : (z == 2) ? w2 : w3;
  unsigned short* dst = dstbase + (size_t)z * W_ELEMS;
  const int t = blockIdx.x * 256 + threadIdx.x;  // 0..131071
  const int o = t >> 7, i0 = (t & 127) << 3;
  const float4* s4 = (const float4*)(src + (size_t)o * 1024 + i0);
  float4 a = s4[0], b = s4[1];
  bf16x8 pk;
  pk[0] = (short)f2bf(a.x); pk[1] = (short)f2bf(a.y);
  pk[2] = (short)f2bf(a.z); pk[3] = (short)f2bf(a.w);
  pk[4] = (short)f2bf(b.x); pk[5] = (short)f2bf(b.y);
  pk[6] = (short)f2bf(b.z); pk[7] = (short)f2bf(b.w);
  size_t addr = ((size_t)((o >> 4) * 32 + (i0 >> 5)) << 9) + (((i0 >> 3) & 3) << 7) + ((o & 15) << 3);
  *(bf16x8*)(dst + addr) = pk;
}

// ---------------------------------------------------------------- projection GEMM (frag-direct)
// C[r][o] = sum_i A[r][i]*W[o][i] + bias[o].  256 thr / 4 waves (2x2 of 64x32).
// Block tile 128x64.  grid (32, 16).
// MODE 0: bh-split K-style frag out (for Q with scale, and K).
// MODE 1: bh-split V-style frag out.
// MODE 2: f32 flat [4096][1024] out.
template <int MODE>
__global__ __launch_bounds__(256) void proj_frag(const unsigned short* __restrict__ Af,
                                                 const unsigned short* __restrict__ Wf,
                                                 const float* __restrict__ bias,
                                                 void* __restrict__ outp, float scale) {
  const int t = threadIdx.x, l = t & 63, w = t >> 6;
  const int wr = w >> 1, wc = w & 1;
  const int bx = blockIdx.x, by = blockIdx.y;

  const unsigned short* a0 = Af + (((size_t)(bx * 8 + wr * 4) * 32) << 9) + l * 8;
  const unsigned short* b0 = Wf + (((size_t)(by * 4 + wc * 2) * 32) << 9) + l * 8;

  f32x4 acc[4][2];
#pragma unroll
  for (int m = 0; m < 4; ++m)
#pragma unroll
    for (int n = 0; n < 2; ++n) acc[m][n] = {0.f, 0.f, 0.f, 0.f};

#pragma unroll 4
  for (int c = 0; c < 32; ++c) {
    bf16x8 af[4], bfr[2];
#pragma unroll
    for (int m = 0; m < 4; ++m)
      af[m] = *(const bf16x8*)(a0 + (((size_t)(m * 32 + c)) << 9));
#pragma unroll
    for (int n = 0; n < 2; ++n)
      bfr[n] = *(const bf16x8*)(b0 + (((size_t)(n * 32 + c)) << 9));
#pragma unroll
    for (int n = 0; n < 2; ++n)
#pragma unroll
      for (int m = 0; m < 4; ++m)
        acc[m][n] = __builtin_amdgcn_mfma_f32_16x16x32_bf16(af[m], bfr[n], acc[m][n], 0, 0, 0);
  }

  const int l4 = (l >> 4) << 2, cl = l & 15;
#pragma unroll
  for (int n = 0; n < 2; ++n) {
    const int gc = by * 64 + wc * 32 + n * 16 + cl;
    const float bi = bias[gc];
#pragma unroll
    for (int m = 0; m < 4; ++m) {
      const int gr0 = bx * 128 + wr * 64 + m * 16 + l4;
      if (MODE == 2) {
        float* o = (float*)outp;
#pragma unroll
        for (int j = 0; j < 4; ++j)
          o[(size_t)(gr0 + j) * 1024 + gc] = acc[m][n][j] + bi;
      } else {
        const int b = gr0 >> 11, s0 = gr0 & 2047, h = gc >> 6, d = gc & 63;
        const size_t base = (size_t)(b * 16 + h) * BH_ELEMS;
        unsigned short* o = (unsigned short*)outp;
        if (MODE == 0) {
#pragma unroll
          for (int j = 0; j < 4; ++j) {
            const int s = s0 + j;
            size_t addr = base + ((size_t)((s >> 4) * 2 + (d >> 5)) << 9) +
                          (((d >> 3) & 3) << 7) + ((s & 15) << 3) + (d & 7);
            o[addr] = f2bf((acc[m][n][j] + bi) * scale);
          }
        } else {
          size_t addr = base + ((size_t)((s0 >> 5) * 4 + (d >> 4)) << 9) +
                        (((s0 >> 3) & 3) << 7) + ((d & 15) << 3) + (s0 & 7);
          u16x4 pk;
#pragma unroll
          for (int j = 0; j < 4; ++j) pk[j] = f2bf(acc[m][n][j] + bi);
          *(u16x4*)(o + addr) = pk;
        }
      }
    }
  }
}

// ---------------------------------------------------------------- attention
// One block = one (b,h) x 16 query rows. 512 thr / 8 waves.
// Wave w owns score col-groups {ct*8 + w}. K/V fragments direct from global
// (L2-hot via XCD swizzle). No barriers until softmax reduce.
__global__ __launch_bounds__(512) void attn_v2(const unsigned short* __restrict__ Qf,
                                               const unsigned short* __restrict__ Kf,
                                               const unsigned short* __restrict__ Vf,
                                               const int* __restrict__ mask,
                                               const int* __restrict__ flag,
                                               float* __restrict__ Pout,
                                               unsigned short* __restrict__ ctxf) {
  __shared__ short lP[16 * 1024];   // 32 KB: P half bf16 (swizzled) / f32 reduce scratch
  __shared__ float rred[8][16];

  const int t = threadIdx.x, l = t & 63, w = t >> 6;
  const int bid = blockIdx.x;
  const int swz = (bid & 7) * 512 + (bid >> 3);   // bijective: 4096 % 8 == 0
  const int bh = swz >> 7, rt = swz & 127;
  const int q0 = rt * 16;

  const unsigned short* qf = Qf + (size_t)bh * BH_ELEMS + l * 8;
  const unsigned short* kf = Kf + (size_t)bh * BH_ELEMS + l * 8;
  const unsigned short* vf = Vf + (size_t)bh * BH_ELEMS + l * 8;

  const bf16x8 aq0 = *(const bf16x8*)(qf + ((size_t)(rt * 2) << 9));
  const bf16x8 aq1 = *(const bf16x8*)(qf + ((size_t)(rt * 2 + 1) << 9));

  f32x4 sacc[16];
#pragma unroll
  for (int ct = 0; ct < 16; ++ct) {
    const int g = ct * 8 + w;
    bf16x8 bk0 = *(const bf16x8*)(kf + ((size_t)(g * 2) << 9));
    bf16x8 bk1 = *(const bf16x8*)(kf + ((size_t)(g * 2 + 1) << 9));
    f32x4 s = {0.f, 0.f, 0.f, 0.f};
    s = __builtin_amdgcn_mfma_f32_16x16x32_bf16(aq0, bk0, s, 0, 0, 0);
    s = __builtin_amdgcn_mfma_f32_16x16x32_bf16(aq1, bk1, s, 0, 0, 0);
    sacc[ct] = s;
    if ((ct & 3) == 3) __builtin_amdgcn_sched_barrier(0);
  }

  // ---- mask slow path
  const bool allones = (*flag != 0);
  const int l4 = (l >> 4) << 2;
  if (!allones) {
#pragma unroll
    for (int ct = 0; ct < 16; ++ct) {
      int col = ct * 128 + w * 16 + (l & 15);
#pragma unroll
      for (int j = 0; j < 4; ++j)
        if (mask[(size_t)(q0 + l4 + j) * S + col] == 0) sacc[ct][j] = -1e9f;
    }
  }

  // ---- softmax: row r = l4+j lives across lanes (l&15) x 8 waves
  float mrow[4];
#pragma unroll
  for (int j = 0; j < 4; ++j) {
    float m = sacc[0][j];
#pragma unroll
    for (int ct = 1; ct < 16; ++ct) m = fmaxf(m, sacc[ct][j]);
#pragma unroll
    for (int off = 1; off < 16; off <<= 1) m = fmaxf(m, __shfl_xor(m, off));
    mrow[j] = m;
  }
  if ((l & 15) == 0) {
#pragma unroll
    for (int j = 0; j < 4; ++j) rred[w][l4 + j] = mrow[j];
  }
  __syncthreads();
#pragma unroll
  for (int j = 0; j < 4; ++j) {
    float m = rred[0][l4 + j];
#pragma unroll
    for (int ww = 1; ww < 8; ++ww) m = fmaxf(m, rred[ww][l4 + j]);
    mrow[j] = m;
  }
  __syncthreads();

  float zsum[4] = {0.f, 0.f, 0.f, 0.f};
#pragma unroll
  for (int ct = 0; ct < 16; ++ct)
#pragma unroll
    for (int j = 0; j < 4; ++j) {
      float p = __expf(sacc[ct][j] - mrow[j]);
      sacc[ct][j] = p;
      zsum[j] += p;
    }
#pragma unroll
  for (int j = 0; j < 4; ++j) {
    float s = zsum[j];
#pragma unroll
    for (int off = 1; off < 16; off <<= 1) s += __shfl_xor(s, off);
    zsum[j] = s;
  }
  if ((l & 15) == 0) {
#pragma unroll
    for (int j = 0; j < 4; ++j) rred[w][l4 + j] = zsum[j];
  }
  __syncthreads();
  float inv[4];
#pragma unroll
  for (int j = 0; j < 4; ++j) {
    float z = rred[0][l4 + j];
#pragma unroll
    for (int ww = 1; ww < 8; ++ww) z += rred[ww][l4 + j];
    inv[j] = 1.0f / z;
  }

  // ---- P write (nontemporal f32) + bf16 to swizzled LDS; PV in two halves
  float* Prow = Pout + ((size_t)bh * S + q0) * S;
  f32x4 pacc[4];
#pragma unroll
  for (int n = 0; n < 4; ++n) pacc[n] = {0.f, 0.f, 0.f, 0.f};

#pragma unroll
  for (int hf = 0; hf < 2; ++hf) {
#pragma unroll
    for (int c2 = 0; c2 < 8; ++c2) {
      int ct = hf * 8 + c2;
      int col = ct * 128 + w * 16 + (l & 15);
      int ccol = col - hf * 1024;
#pragma unroll
      for (int j = 0; j < 4; ++j) {
        int r = l4 + j;
        float pv = sacc[ct][j] * inv[j];
        __builtin_nontemporal_store(pv, &Prow[(size_t)r * S + col]);
        int byte = (r * 2048 + ccol * 2) ^ ((r & 7) << 4);
        *(unsigned short*)((char*)lP + byte) = f2bf(pv);
      }
    }
    __syncthreads();
    // PV: wave w handles k in [hf*1024 + w*128, +128)
#pragma unroll
    for (int kk = 0; kk < 4; ++kk) {
      int kb = w * 128 + kk * 32;
      int row = l & 15;
      int byteA = (row * 2048 + (kb + (l >> 4) * 8) * 2) ^ ((row & 7) << 4);
      bf16x8 ap = *(const bf16x8*)((const char*)lP + byteA);
      const int kbi = hf * 32 + w * 4 + kk;
#pragma unroll
      for (int n = 0; n < 4; ++n) {
        bf16x8 bv = *(const bf16x8*)(vf + ((size_t)(kbi * 4 + n) << 9));
        pacc[n] = __builtin_amdgcn_mfma_f32_16x16x32_bf16(ap, bv, pacc[n], 0, 0, 0);
      }
      __builtin_amdgcn_sched_barrier(0);
    }
    __syncthreads();
  }

  // ---- cross-wave K-slice reduce via lP (f32 [8][1024]) -> ctx A-frag out
  float* red = (float*)lP;
#pragma unroll
  for (int n = 0; n < 4; ++n)
#pragma unroll
    for (int j = 0; j < 4; ++j)
      red[w * 1024 + (l4 + j) * 64 + n * 16 + (l & 15)] = pacc[n][j];
  __syncthreads();
  const int b = bh >> 4, h = bh & 15;
#pragma unroll
  for (int i = 0; i < 2; ++i) {
    int idx = t * 2 + i;
    float s = red[idx];
#pragma unroll
    for (int ww = 1; ww < 8; ++ww) s += red[ww * 1024 + idx];
    int qrow = idx >> 6, d = idx & 63;
    // ctx A-frag: token r = b*2048 + q0 + qrow (g = b*128+rt, cl = qrow), ch = h*64+d
    size_t addr = ((size_t)((b * 128 + rt) * 32 + h * 2 + (d >> 5)) << 9) +
                  (((d >> 3) & 3) << 7) + (qrow << 3) + (d & 7);
    ctxf[addr] = f2bf(s);
  }
}

// ---------------------------------------------------------------- launch
extern "C" void kernel_launch(void* const* d_in, const int* in_sizes, int n_in,
                              void* d_out, int out_size, void* d_ws, size_t ws_size,
                              hipStream_t stream) {
  const float* q = (const float*)d_in[0];
  const float* k = (const float*)d_in[1];
  const float* v = (const float*)d_in[2];
  const int* mask = (const int*)d_in[3];
  const float* w_q = (const float*)d_in[4];
  const float* b_q = (const float*)d_in[5];
  const float* w_k = (const float*)d_in[6];
  const float* b_k = (const float*)d_in[7];
  const float* w_v = (const float*)d_in[8];
  const float* b_v = (const float*)d_in[9];
  const float* w_o = (const float*)d_in[10];
  const float* b_o = (const float*)d_in[11];

  unsigned short* wsu = (unsigned short*)d_ws;
  unsigned short* A0 = wsu + 0 * A_ELEMS;  // qbf -> khf
  unsigned short* A1 = wsu + 1 * A_ELEMS;  // kbf -> vhf
  unsigned short* A2 = wsu + 2 * A_ELEMS;  // vbf -> ctxf
  unsigned short* A3 = wsu + 3 * A_ELEMS;  // qhf
  unsigned short* Wb = wsu + 4 * A_ELEMS;  // wqf|wkf|wvf|wof
  unsigned short* wqf = Wb + 0 * W_ELEMS;
  unsigned short* wkf = Wb + 1 * W_ELEMS;
  unsigned short* wvf = Wb + 2 * W_ELEMS;
  unsigned short* wof = Wb + 3 * W_ELEMS;
  int* flag = (int*)(Wb + 4 * W_ELEMS);

  float* out_f = (float*)d_out;                  // [4096][1024]
  float* attnW = out_f + (size_t)4096 * 1024;    // [2][16][2048][2048]

  flag_init_kernel<<<1, 1, 0, stream>>>(flag);
  mask_and_kernel<<<1024, 256, 0, stream>>>(mask, flag);

  convert_a<<<dim3(2048, 3), 256, 0, stream>>>(q, k, v, A0, A1, A2);
  convert_w<<<dim3(512, 4), 256, 0, stream>>>(w_q, w_k, w_v, w_o, Wb);

  const float qscale = 0.125f;  // 1/sqrt(64)
  proj_frag<0><<<dim3(32, 16), 256, 0, stream>>>(A0, wqf, b_q, (void*)A3, qscale);  // Q
  proj_frag<0><<<dim3(32, 16), 256, 0, stream>>>(A1, wkf, b_k, (void*)A0, 1.0f);    // K
  proj_frag<1><<<dim3(32, 16), 256, 0, stream>>>(A2, wvf, b_v, (void*)A1, 1.0f);    // V

  attn_v2<<<4096, 512, 0, stream>>>(A3, A0, A1, mask, flag, attnW, A2);

  proj_frag<2><<<dim3(32, 16), 256, 0, stream>>>(A2, wof, b_o, (void*)d_out, 1.0f); // O
}